// Round 7
// baseline (710.037 us; speedup 1.0000x reference)
//
#include <hip/hip_runtime.h>

#define Mc 512
#define Nc 1024
#define WRc 16
#define Bc 4096

// Layered min-sum; 16 lanes = one check-node row, 4 batch elems / wave.
// R7: per-step metadata is a fused, precomputed ushort stream g_idx
// (helper kernel: g_idx[s*16+j] = H[cn_order[s]*16+j]; 16 KB, L1-hot,
// sequential) -> the main loop has ONE global ushort load per step and no
// index chase. Sweep 0 (t<508) peeled: no FIFO reads/reconstruct there.
// Compressed row state FIFO in LDS (slot s = t mod 512; write t, read t+4):
//   stAB = (m1c, m2c) clipped min/2nd-min bits, stC = signs16|a1<<16|tp<<20
//   c2v_j = (j==a1 ? m2c : m1c) signed by (tp ^ sign_j)  [bit-exact, ties ok]
// LDS = 16K vn + 16K stAB + 8K stC = 40960 B -> exactly 4 blocks/CU.

__device__ unsigned short g_idx[Mc * WRc];  // fused index stream (16 KB)

#define DPPI(old, src, ctrl) \
  __builtin_amdgcn_update_dpp((old), (src), (ctrl), 0xF, 0xF, false)

static __device__ __forceinline__ int imin(int a, int b) { return a < b ? a : b; }
static __device__ __forceinline__ int imax(int a, int b) { return a > b ? a : b; }

#define CLIPB 0x41A00000  /* bits of 20.0f */
#define INFB  0x7F800000

__global__ void build_idx(const int* __restrict__ H,
                          const int* __restrict__ cn_order) {
  const int i = blockIdx.x * 1024 + threadIdx.x;   // grid 8 x 1024 = 8192
  if (i < Mc * WRc)
    g_idx[i] = (unsigned short)H[cn_order[i >> 4] * WRc + (i & 15)];
}

__global__ __launch_bounds__(64) void ldpc_kernel(
    const float* __restrict__ llr, const int* __restrict__ iters_p,
    float* __restrict__ out) {
  const int tid = threadIdx.x;
  const int g = tid >> 4;    // batch sub-slot (0..3) == DPP row
  const int j = tid & 15;    // edge position in the check node
  const int b0 = blockIdx.x * 4;

  __shared__ float vn[4][Nc];          // 16 KB
  __shared__ uint2 stAB[Mc * 4];       // 16 KB: (m1c, m2c) per (slot, g)
  __shared__ unsigned stC[Mc * 4];     //  8 KB: signs16 | a1<<16 | tp<<20

  for (int i = tid; i < 4 * Nc; i += 64)
    vn[i >> 10][i & (Nc - 1)] = llr[(size_t)(b0 + (i >> 10)) * Nc + (i & (Nc - 1))];
  __syncthreads();

  const int T = iters_p[0] * Mc;       // iters*512, multiple of 4
  const int shft = g * 16;
  const unsigned short* const sp = g_idx + j;   // lane-const stream base

  // ---- prime the index queue (depth 5) + first gather ----
  int i0 = (int)sp[0 * WRc];
  int i1 = (int)sp[1 * WRc];
  int i2 = (int)sp[2 * WRc];
  int i3 = (int)sp[3 * WRc];
  int i4 = (int)sp[4 * WRc];
  float v = vn[g][i0];                 // gather for t=0
  float c2vf[4] = {0.0f, 0.0f, 0.0f, 0.0f};

  const int A_end = (T >= Mc) ? (Mc - 4) : T;   // 508 (mult. of 4), or all

  int t = 0;
  // ================= Loop A: sweep 0 (c2v == 0, no FIFO reads) ============
  for (; t < A_end; t += 4) {
#pragma unroll
    for (int k = 0; k < 4; ++k) {
      const int tt = t + k;
      const float v2c = v;                       // c2v is zero in sweep 0
      const int ab = __float_as_int(v2c) & 0x7FFFFFFF;

      int p = ab;
      p = imin(p, DPPI(INFB, p, 0x111));
      p = imin(p, DPPI(INFB, p, 0x112));
      p = imin(p, DPPI(INFB, p, 0x114));
      p = imin(p, DPPI(INFB, p, 0x118));
      int s = ab;
      s = imin(s, DPPI(INFB, s, 0x101));
      s = imin(s, DPPI(INFB, s, 0x102));
      s = imin(s, DPPI(INFB, s, 0x104));
      s = imin(s, DPPI(INFB, s, 0x108));
      const int pe = DPPI(INFB, p, 0x111);
      const int se = DPPI(INFB, s, 0x101);
      const int loo = imin(pe, se);
      const int ampi = imin(loo, CLIPB);

      const unsigned long long sbal = __ballot(v2c < 0.0f);
      const unsigned sgn16 = ((unsigned)(sbal >> shft)) & 0xFFFFu;
      const unsigned tp = (unsigned)__popc(sgn16) & 1u;
      const unsigned sb = ((unsigned)__float_as_int(v2c)) >> 31;
      const float nc = __uint_as_float((unsigned)ampi | ((tp ^ sb) << 31));

      vn[g][i0] = v2c + nc;     // scatter (slot tt)
      v = vn[g][i1];            // gather (slot tt+1)

      // FIFO write (consumed one sweep later)
      const int m1 = imin(loo, ab);
      const unsigned long long mbal = __ballot(ab == m1);
      const int a1 = __ffs((unsigned)((mbal >> shft) & 0xFFFFu)) - 1;
      int mx = loo;
      mx = imax(mx, DPPI(0, mx, 0x121));
      mx = imax(mx, DPPI(0, mx, 0x122));
      mx = imax(mx, DPPI(0, mx, 0x124));
      mx = imax(mx, DPPI(0, mx, 0x128));
      const int wsl = (tt & (Mc - 1)) * 4 + g;
      if (j == 0) {
        stAB[wsl] = make_uint2((unsigned)imin(m1, CLIPB),
                               (unsigned)imin(mx, CLIPB));
        stC[wsl] = sgn16 | ((unsigned)a1 << 16) | (tp << 20);
      }

      i0 = i1; i1 = i2; i2 = i3; i3 = i4;       // rotate index queue
      i4 = (int)sp[((tt + 5) & (Mc - 1)) * WRc];
    }
  }

  // ================= Loop B: steady state (full body, no mask) ============
  for (; t < T; t += 4) {
#pragma unroll
    for (int k = 0; k < 4; ++k) {
      const int tt = t + k;
      const float v2c = v - c2vf[k];
      const int ab = __float_as_int(v2c) & 0x7FFFFFFF;

      int p = ab;
      p = imin(p, DPPI(INFB, p, 0x111));
      p = imin(p, DPPI(INFB, p, 0x112));
      p = imin(p, DPPI(INFB, p, 0x114));
      p = imin(p, DPPI(INFB, p, 0x118));
      int s = ab;
      s = imin(s, DPPI(INFB, s, 0x101));
      s = imin(s, DPPI(INFB, s, 0x102));
      s = imin(s, DPPI(INFB, s, 0x104));
      s = imin(s, DPPI(INFB, s, 0x108));
      const int pe = DPPI(INFB, p, 0x111);
      const int se = DPPI(INFB, s, 0x101);
      const int loo = imin(pe, se);
      const int ampi = imin(loo, CLIPB);

      const unsigned long long sbal = __ballot(v2c < 0.0f);
      const unsigned sgn16 = ((unsigned)(sbal >> shft)) & 0xFFFFu;
      const unsigned tp = (unsigned)__popc(sgn16) & 1u;
      const unsigned sb = ((unsigned)__float_as_int(v2c)) >> 31;
      const float nc = __uint_as_float((unsigned)ampi | ((tp ^ sb) << 31));

      vn[g][i0] = v2c + nc;     // scatter (slot tt)
      v = vn[g][i1];            // gather (slot tt+1)

      // FIFO write
      const int m1 = imin(loo, ab);
      const unsigned long long mbal = __ballot(ab == m1);
      const int a1 = __ffs((unsigned)((mbal >> shft) & 0xFFFFu)) - 1;
      int mx = loo;
      mx = imax(mx, DPPI(0, mx, 0x121));
      mx = imax(mx, DPPI(0, mx, 0x122));
      mx = imax(mx, DPPI(0, mx, 0x124));
      mx = imax(mx, DPPI(0, mx, 0x128));
      const int wsl = (tt & (Mc - 1)) * 4 + g;
      if (j == 0) {
        stAB[wsl] = make_uint2((unsigned)imin(m1, CLIPB),
                               (unsigned)imin(mx, CLIPB));
        stC[wsl] = sgn16 | ((unsigned)a1 << 16) | (tp << 20);
      }

      // FIFO read + reconstruct for step tt+4 (t4 >= 512 always here)
      const int rsl = ((tt + 4) & (Mc - 1)) * 4 + g;
      const uint2 mm = stAB[rsl];
      const unsigned met = stC[rsl];
      const unsigned psb = (met >> j) & 1u;
      const unsigned ptp = (met >> 20) & 1u;
      const unsigned pai = (j == (int)((met >> 16) & 15u)) ? mm.y : mm.x;
      c2vf[k] = __uint_as_float(pai | ((ptp ^ psb) << 31));

      i0 = i1; i1 = i2; i2 = i3; i3 = i4;       // rotate index queue
      i4 = (int)sp[((tt + 5) & (Mc - 1)) * WRc];
    }
  }

  // Hard decision. Single-wave block: wave-synchronous, no barrier needed.
  for (int i = tid; i < 4 * Nc; i += 64) {
    const int gg = i >> 10, n = i & (Nc - 1);
    out[(size_t)(b0 + gg) * Nc + n] = (vn[gg][n] < 0.0f) ? 1.0f : 0.0f;
  }
}

extern "C" void kernel_launch(void* const* d_in, const int* in_sizes, int n_in,
                              void* d_out, int out_size, void* d_ws, size_t ws_size,
                              hipStream_t stream) {
  const float* llr = (const float*)d_in[0];
  const int* H = (const int*)d_in[1];
  const int* iters_p = (const int*)d_in[2];
  const int* cn_order = (const int*)d_in[3];
  float* out = (float*)d_out;
  build_idx<<<dim3(8), dim3(1024), 0, stream>>>(H, cn_order);
  ldpc_kernel<<<dim3(Bc / 4), dim3(64), 0, stream>>>(llr, iters_p, out);
}